// Round 5
// baseline (172.539 us; speedup 1.0000x reference)
//
#include <hip/hip_runtime.h>

// PerturbedTopK: B=128, N=1000, D=196, K=48, sigma=0.05
//
// Per (b,n) row: exact top-K of x[b,:] + sigma*noise[b,n,:], tie-break lowest
// index first (jax.lax.top_k), then scatter 1/N at (b, rank_by_index, d).
//
// R5 = R4 with compile fix (ds_swizzle pattern must be a frontend constant ->
// template parameter). R4 theory vs R3 (ptopk ~56us, instruction-bound):
//  - float-domain compares (no u32 key transform): -12 VALU/row.
//  - peel-to-selection: sel = (v > piv); c==48 -> done (no cross-lane work);
//    c>48 -> peel (c-48) minima out of sel (ties: drop highest d);
//    c<48 -> peel (48-c) maxima of the rest in (ties: add lowest d).
//  - expected peel iterations = E|c-48| ~ 2.3 (float ties ~impossible).
//  Fixed harness reset (~112us: 392MB d_ws poison + input restore) dominates
//  reported dur_us; ptopk target ~15-25us.

#define BB 128
#define NN 1000
#define DD 196
#define KK 48

constexpr int SPLIT   = 8;            // blocks per b (n-range split)
constexpr int ROWS    = NN / SPLIT;   // 125 rows per block
constexpr int THREADS = 512;          // 8 waves -> 4 blocks/CU = 32 waves/CU
constexpr int NWAVES  = THREADS / 64;
constexpr int DH      = DD / 2;       // 98 packed columns
constexpr int LDSN    = KK * DH;      // 4704 u32

__device__ __forceinline__ int mbcnt64(unsigned long long m) {
  return __builtin_amdgcn_mbcnt_hi((unsigned)(m >> 32),
         __builtin_amdgcn_mbcnt_lo((unsigned)m, 0));
}

template <int PAT>
__device__ __forceinline__ float swz(float v) {
  return __int_as_float(__builtin_amdgcn_ds_swizzle(__float_as_int(v), PAT));
}

// wave-uniform min/max over 64 lanes: 5 ds_swizzle xor-levels (32-lane groups)
// + readlane(0)/readlane(32) + scalar combine.
__device__ __forceinline__ float wave_min_f32(float m) {
  m = fminf(m, swz<0x041F>(m));  // ^1
  m = fminf(m, swz<0x081F>(m));  // ^2
  m = fminf(m, swz<0x101F>(m));  // ^4
  m = fminf(m, swz<0x201F>(m));  // ^8
  m = fminf(m, swz<0x401F>(m));  // ^16
  float a = __int_as_float(__builtin_amdgcn_readlane(__float_as_int(m), 0));
  float b = __int_as_float(__builtin_amdgcn_readlane(__float_as_int(m), 32));
  return fminf(a, b);
}
__device__ __forceinline__ float wave_max_f32(float m) {
  m = fmaxf(m, swz<0x041F>(m));
  m = fmaxf(m, swz<0x081F>(m));
  m = fmaxf(m, swz<0x101F>(m));
  m = fmaxf(m, swz<0x201F>(m));
  m = fmaxf(m, swz<0x401F>(m));
  float a = __int_as_float(__builtin_amdgcn_readlane(__float_as_int(m), 0));
  float b = __int_as_float(__builtin_amdgcn_readlane(__float_as_int(m), 32));
  return fmaxf(a, b);
}

__device__ __forceinline__ unsigned key_of(float v) {
  unsigned u = __float_as_uint(v);
  return u ^ (0x80000000u | (unsigned)((int)u >> 31));
}

// piv[b] = exact 48th-largest VALUE of x[b] (as float); one wave per b.
// Bisection on monotonic keys, then inverse-map key -> float.
__global__ __launch_bounds__(64) void pivot_kernel(
    const float* __restrict__ x, float* __restrict__ piv) {
  const int b    = blockIdx.x;
  const int lane = threadIdx.x;
  const bool lv  = lane < 49;
  float4 xv = make_float4(0.f, 0.f, 0.f, 0.f);
  if (lv) xv = *reinterpret_cast<const float4*>(x + b * DD + 4 * lane);
  unsigned xk0 = lv ? key_of(xv.x) : 0u;
  unsigned xk1 = lv ? key_of(xv.y) : 0u;
  unsigned xk2 = lv ? key_of(xv.z) : 0u;
  unsigned xk3 = lv ? key_of(xv.w) : 0u;
  unsigned p = 0u;
  #pragma unroll
  for (int bit = 31; bit >= 0; --bit) {
    unsigned cand = p | (1u << bit);
    int c = __popcll(__ballot(xk0 >= cand)) + __popcll(__ballot(xk1 >= cand))
          + __popcll(__ballot(xk2 >= cand)) + __popcll(__ballot(xk3 >= cand));
    if (c >= KK) p = cand;
  }
  if (lane == 0) {
    // inverse of key_of: top bit set -> positive float; else negative
    unsigned u = (p & 0x80000000u) ? (p ^ 0x80000000u) : ~p;
    piv[b] = __uint_as_float(u);
  }
}

__global__ __launch_bounds__(THREADS) void ptopk_kernel(
    const float* __restrict__ x, const float* __restrict__ noise,
    const float* __restrict__ sigp, const float* __restrict__ pivp,
    float* __restrict__ out) {
  __shared__ unsigned cnt[LDSN];
  const int tid   = threadIdx.x;
  const int b     = blockIdx.x / SPLIT;
  const int split = blockIdx.x % SPLIT;

  for (int i = tid; i < LDSN; i += THREADS) cnt[i] = 0u;
  __syncthreads();

  const float sigma = sigp[0];
  const float piv   = pivp[b];
  const int lane = tid & 63;
  const int wv   = tid >> 6;
  const bool lv  = lane < 49;  // 49 lanes * 4 floats = 196 = D
  const float PINF = __builtin_huge_valf();
  const float NINF = -__builtin_huge_valf();

  float4 xv = make_float4(0.f, 0.f, 0.f, 0.f);
  if (lv) xv = *reinterpret_cast<const float4*>(x + b * DD + 4 * lane);

  const float* nbase = noise + ((size_t)b * NN + (size_t)split * ROWS) * DD;

  // prefetched next-row noise
  float4 nv = make_float4(0.f, 0.f, 0.f, 0.f);
  if (lv && wv < ROWS)
    nv = *reinterpret_cast<const float4*>(nbase + (size_t)wv * DD + 4 * lane);

  for (int r = wv; r < ROWS; r += NWAVES) {
    const float4 cur = nv;
    if (lv && (r + NWAVES) < ROWS)
      nv = *reinterpret_cast<const float4*>(nbase + (size_t)(r + NWAVES) * DD + 4 * lane);

    // perturbed values; inactive lanes -> -inf (never selected)
    const float v0 = lv ? fmaf(sigma, cur.x, xv.x) : NINF;
    const float v1 = lv ? fmaf(sigma, cur.y, xv.y) : NINF;
    const float v2 = lv ? fmaf(sigma, cur.z, xv.z) : NINF;
    const float v3 = lv ? fmaf(sigma, cur.w, xv.w) : NINF;

    bool s0 = v0 > piv, s1 = v1 > piv, s2 = v2 > piv, s3 = v3 > piv;
    unsigned long long S0 = __ballot(s0), S1 = __ballot(s1),
                       S2 = __ballot(s2), S3 = __ballot(s3);
    const int c = __popcll(S0) + __popcll(S1) + __popcll(S2) + __popcll(S3);

    if (c > KK) {
      // remove the (c-K) smallest of the selected set; ties: drop highest d
      int need = c - KK;
      float m0 = s0 ? v0 : PINF, m1 = s1 ? v1 : PINF;
      float m2 = s2 ? v2 : PINF, m3 = s3 ? v3 : PINF;
      for (;;) {
        const float mm = wave_min_f32(fminf(fminf(m0, m1), fminf(m2, m3)));
        const bool e0 = (m0 == mm), e1 = (m1 == mm),
                   e2 = (m2 == mm), e3 = (m3 == mm);
        const unsigned long long E0 = __ballot(e0), E1 = __ballot(e1),
                                 E2 = __ballot(e2), E3 = __ballot(e3);
        const int cv = __popcll(E0) + __popcll(E1) + __popcll(E2) + __popcll(E3);
        if (cv <= need) {
          s0 &= !e0; s1 &= !e1; s2 &= !e2; s3 &= !e3;
          need -= cv;
          if (need == 0) break;
          m0 = e0 ? PINF : m0; m1 = e1 ? PINF : m1;
          m2 = e2 ? PINF : m2; m3 = e3 ? PINF : m3;
        } else {
          const int keep = cv - need;  // lowest-d `keep` ties stay selected
          int tp = mbcnt64(E0) + mbcnt64(E1) + mbcnt64(E2) + mbcnt64(E3);
          if (e0 && tp >= keep) s0 = false;  tp += e0 ? 1 : 0;
          if (e1 && tp >= keep) s1 = false;  tp += e1 ? 1 : 0;
          if (e2 && tp >= keep) s2 = false;  tp += e2 ? 1 : 0;
          if (e3 && tp >= keep) s3 = false;
          break;
        }
      }
      S0 = __ballot(s0); S1 = __ballot(s1); S2 = __ballot(s2); S3 = __ballot(s3);
    } else if (c < KK) {
      // add the (K-c) largest of the unselected rest; ties: add lowest d
      int need = KK - c;
      float m0 = s0 ? NINF : v0, m1 = s1 ? NINF : v1;
      float m2 = s2 ? NINF : v2, m3 = s3 ? NINF : v3;
      for (;;) {
        const float mm = wave_max_f32(fmaxf(fmaxf(m0, m1), fmaxf(m2, m3)));
        const bool e0 = (m0 == mm), e1 = (m1 == mm),
                   e2 = (m2 == mm), e3 = (m3 == mm);
        const unsigned long long E0 = __ballot(e0), E1 = __ballot(e1),
                                 E2 = __ballot(e2), E3 = __ballot(e3);
        const int cv = __popcll(E0) + __popcll(E1) + __popcll(E2) + __popcll(E3);
        if (cv <= need) {
          s0 |= e0; s1 |= e1; s2 |= e2; s3 |= e3;
          need -= cv;
          if (need == 0) break;
          m0 = e0 ? NINF : m0; m1 = e1 ? NINF : m1;
          m2 = e2 ? NINF : m2; m3 = e3 ? NINF : m3;
        } else {
          int tp = mbcnt64(E0) + mbcnt64(E1) + mbcnt64(E2) + mbcnt64(E3);
          if (e0 && tp < need) s0 = true;  tp += e0 ? 1 : 0;
          if (e1 && tp < need) s1 = true;  tp += e1 ? 1 : 0;
          if (e2 && tp < need) s2 = true;  tp += e2 ? 1 : 0;
          if (e3 && tp < need) s3 = true;
          break;
        }
      }
      S0 = __ballot(s0); S1 = __ballot(s1); S2 = __ballot(s2); S3 = __ballot(s3);
    }
    // c == KK: sel already exact, ballots already computed.

    // rank-by-index k = prefix count of selected below d (d = 4*lane + s)
    int kp = mbcnt64(S0) + mbcnt64(S1) + mbcnt64(S2) + mbcnt64(S3);
    const int b2 = 2 * lane;  // packed col: d=4l..4l+1 -> 2l, d=4l+2..3 -> 2l+1
    if (s0) atomicAdd(&cnt[kp * DH + b2],     1u);        kp += s0 ? 1 : 0;
    if (s1) atomicAdd(&cnt[kp * DH + b2],     0x10000u);  kp += s1 ? 1 : 0;
    if (s2) atomicAdd(&cnt[kp * DH + b2 + 1], 1u);        kp += s2 ? 1 : 0;
    if (s3) atomicAdd(&cnt[kp * DH + b2 + 1], 0x10000u);
  }

  __syncthreads();

  // sparse flush: count * (1/N) into zero-initialized out
  const float invn = 1.0f / (float)NN;
  float* ob = out + (size_t)b * KK * DD;
  for (int i = tid; i < LDSN; i += THREADS) {
    const unsigned cv = cnt[i];
    if (cv) {
      const int k   = i / DH;
      const int dd2 = i - k * DH;
      const unsigned lo = cv & 0xFFFFu, hi = cv >> 16;
      float* p = ob + k * DD + 2 * dd2;
      if (lo) atomicAdd(p,     (float)lo * invn);
      if (hi) atomicAdd(p + 1, (float)hi * invn);
    }
  }
}

extern "C" void kernel_launch(void* const* d_in, const int* in_sizes, int n_in,
                              void* d_out, int out_size, void* d_ws, size_t ws_size,
                              hipStream_t stream) {
  (void)in_sizes; (void)n_in; (void)ws_size;
  const float* x     = (const float*)d_in[0];
  const float* noise = (const float*)d_in[1];
  const float* sig   = (const float*)d_in[2];
  float* out = (float*)d_out;
  float* piv = (float*)d_ws;

  (void)hipMemsetAsync(d_out, 0, (size_t)out_size * sizeof(float), stream);
  pivot_kernel<<<dim3(BB), dim3(64), 0, stream>>>(x, piv);
  ptopk_kernel<<<dim3(BB * SPLIT), dim3(THREADS), 0, stream>>>(x, noise, sig, piv, out);
}

// Round 6
// 170.439 us; speedup vs baseline: 1.0123x; 1.0123x over previous
//
#include <hip/hip_runtime.h>

// PerturbedTopK: B=128, N=1000, D=196, K=48, sigma=0.05
//
// Per (b,n) row: exact top-K of x[b,:] + sigma*noise[b,n,:], tie-break lowest
// index first (jax.lax.top_k), then scatter 1/N at (b, rank_by_index, d).
//
// R6 vs R5 (ptopk flat at ~58us, VALUBusy 35% -> NOT valu-bound; diagnosis:
// dependent ds_swizzle chains (~60-120cy/hop on LDS pipe) dominate per-row
// critical path):
//  - wave min/max via DPP on the VALU pipe: row_shr:1/2/4/8 + row_bcast15/31
//    (__builtin_amdgcn_update_dpp) + readlane(63). 6 short VALU hops replace
//    5 long LDS hops; LDS pipe freed for the atomics.
//  - 256-thread blocks, grid=2048 (SPLIT=16): de-risks the 512-thread
//    residency anomaly (occupancy read 52% at expected 100%); 8 blocks/CU
//    target (LDS 8 x 18.9KB = 151.5KB <= 160KB).

#define BB 128
#define NN 1000
#define DD 196
#define KK 48

constexpr int SPLIT   = 16;           // blocks per b (n-range split)
constexpr int THREADS = 256;          // 4 waves
constexpr int NWAVES  = THREADS / 64;
constexpr int DH      = DD / 2;       // 98 packed columns
constexpr int LDSN    = KK * DH;      // 4704 u32

__device__ __forceinline__ int mbcnt64(unsigned long long m) {
  return __builtin_amdgcn_mbcnt_hi((unsigned)(m >> 32),
         __builtin_amdgcn_mbcnt_lo((unsigned)m, 0));
}

// --- DPP wave reduction (VALU pipe; no LDS traffic) ---------------------
// update_dpp(old, src, ctrl, row_mask, bank_mask, bound_ctrl=false):
// lanes whose DPP source is invalid keep `old`; we pass old=src so the
// combine is a no-op there. ctrl: 0x110|k = row_shr:k, 0x142 = row_bcast15,
// 0x143 = row_bcast31. After the 6 steps lane 63 holds the full reduction.
template <int CTRL>
__device__ __forceinline__ float dpp_min_step(float v) {
  int t = __builtin_amdgcn_update_dpp(__float_as_int(v), __float_as_int(v),
                                      CTRL, 0xF, 0xF, false);
  return fminf(v, __int_as_float(t));
}
template <int CTRL>
__device__ __forceinline__ float dpp_max_step(float v) {
  int t = __builtin_amdgcn_update_dpp(__float_as_int(v), __float_as_int(v),
                                      CTRL, 0xF, 0xF, false);
  return fmaxf(v, __int_as_float(t));
}

__device__ __forceinline__ float wave_min_f32(float m) {
  m = dpp_min_step<0x111>(m);  // row_shr:1
  m = dpp_min_step<0x112>(m);  // row_shr:2
  m = dpp_min_step<0x114>(m);  // row_shr:4
  m = dpp_min_step<0x118>(m);  // row_shr:8  -> lane 15 of each row16 has row min
  m = dpp_min_step<0x142>(m);  // row_bcast15 -> lane31: rows0-1, lane63: rows2-3
  m = dpp_min_step<0x143>(m);  // row_bcast31 -> lane63: all 64
  return __int_as_float(__builtin_amdgcn_readlane(__float_as_int(m), 63));
}
__device__ __forceinline__ float wave_max_f32(float m) {
  m = dpp_max_step<0x111>(m);
  m = dpp_max_step<0x112>(m);
  m = dpp_max_step<0x114>(m);
  m = dpp_max_step<0x118>(m);
  m = dpp_max_step<0x142>(m);
  m = dpp_max_step<0x143>(m);
  return __int_as_float(__builtin_amdgcn_readlane(__float_as_int(m), 63));
}

__device__ __forceinline__ unsigned key_of(float v) {
  unsigned u = __float_as_uint(v);
  return u ^ (0x80000000u | (unsigned)((int)u >> 31));
}

// piv[b] = exact 48th-largest VALUE of x[b] (as float); one wave per b.
__global__ __launch_bounds__(64) void pivot_kernel(
    const float* __restrict__ x, float* __restrict__ piv) {
  const int b    = blockIdx.x;
  const int lane = threadIdx.x;
  const bool lv  = lane < 49;
  float4 xv = make_float4(0.f, 0.f, 0.f, 0.f);
  if (lv) xv = *reinterpret_cast<const float4*>(x + b * DD + 4 * lane);
  unsigned xk0 = lv ? key_of(xv.x) : 0u;
  unsigned xk1 = lv ? key_of(xv.y) : 0u;
  unsigned xk2 = lv ? key_of(xv.z) : 0u;
  unsigned xk3 = lv ? key_of(xv.w) : 0u;
  unsigned p = 0u;
  #pragma unroll
  for (int bit = 31; bit >= 0; --bit) {
    unsigned cand = p | (1u << bit);
    int c = __popcll(__ballot(xk0 >= cand)) + __popcll(__ballot(xk1 >= cand))
          + __popcll(__ballot(xk2 >= cand)) + __popcll(__ballot(xk3 >= cand));
    if (c >= KK) p = cand;
  }
  if (lane == 0) {
    unsigned u = (p & 0x80000000u) ? (p ^ 0x80000000u) : ~p;
    piv[b] = __uint_as_float(u);
  }
}

__global__ __launch_bounds__(THREADS) void ptopk_kernel(
    const float* __restrict__ x, const float* __restrict__ noise,
    const float* __restrict__ sigp, const float* __restrict__ pivp,
    float* __restrict__ out) {
  __shared__ unsigned cnt[LDSN];
  const int tid   = threadIdx.x;
  const int b     = blockIdx.x / SPLIT;
  const int split = blockIdx.x % SPLIT;
  const int n0    = (split * NN) / SPLIT;        // 62/63-row ranges
  const int n1    = ((split + 1) * NN) / SPLIT;

  for (int i = tid; i < LDSN; i += THREADS) cnt[i] = 0u;
  __syncthreads();

  const float sigma = sigp[0];
  const float piv   = pivp[b];
  const int lane = tid & 63;
  const int wv   = tid >> 6;
  const bool lv  = lane < 49;  // 49 lanes * 4 floats = 196 = D
  const float PINF = __builtin_huge_valf();
  const float NINF = -__builtin_huge_valf();

  float4 xv = make_float4(0.f, 0.f, 0.f, 0.f);
  if (lv) xv = *reinterpret_cast<const float4*>(x + b * DD + 4 * lane);

  const float* nbase = noise + (size_t)b * NN * DD;

  // prefetched next-row noise
  float4 nv = make_float4(0.f, 0.f, 0.f, 0.f);
  if (lv && (n0 + wv) < n1)
    nv = *reinterpret_cast<const float4*>(nbase + (size_t)(n0 + wv) * DD + 4 * lane);

  for (int r = n0 + wv; r < n1; r += NWAVES) {
    const float4 cur = nv;
    if (lv && (r + NWAVES) < n1)
      nv = *reinterpret_cast<const float4*>(nbase + (size_t)(r + NWAVES) * DD + 4 * lane);

    // perturbed values; inactive lanes -> -inf (never selected)
    const float v0 = lv ? fmaf(sigma, cur.x, xv.x) : NINF;
    const float v1 = lv ? fmaf(sigma, cur.y, xv.y) : NINF;
    const float v2 = lv ? fmaf(sigma, cur.z, xv.z) : NINF;
    const float v3 = lv ? fmaf(sigma, cur.w, xv.w) : NINF;

    bool s0 = v0 > piv, s1 = v1 > piv, s2 = v2 > piv, s3 = v3 > piv;
    unsigned long long S0 = __ballot(s0), S1 = __ballot(s1),
                       S2 = __ballot(s2), S3 = __ballot(s3);
    const int c = __popcll(S0) + __popcll(S1) + __popcll(S2) + __popcll(S3);

    if (c > KK) {
      // remove the (c-K) smallest of the selected set; ties: drop highest d
      int need = c - KK;
      float m0 = s0 ? v0 : PINF, m1 = s1 ? v1 : PINF;
      float m2 = s2 ? v2 : PINF, m3 = s3 ? v3 : PINF;
      for (;;) {
        const float mm = wave_min_f32(fminf(fminf(m0, m1), fminf(m2, m3)));
        const bool e0 = (m0 == mm), e1 = (m1 == mm),
                   e2 = (m2 == mm), e3 = (m3 == mm);
        const unsigned long long E0 = __ballot(e0), E1 = __ballot(e1),
                                 E2 = __ballot(e2), E3 = __ballot(e3);
        const int cv = __popcll(E0) + __popcll(E1) + __popcll(E2) + __popcll(E3);
        if (cv <= need) {
          s0 &= !e0; s1 &= !e1; s2 &= !e2; s3 &= !e3;
          need -= cv;
          if (need == 0) break;
          m0 = e0 ? PINF : m0; m1 = e1 ? PINF : m1;
          m2 = e2 ? PINF : m2; m3 = e3 ? PINF : m3;
        } else {
          const int keep = cv - need;  // lowest-d `keep` ties stay selected
          int tp = mbcnt64(E0) + mbcnt64(E1) + mbcnt64(E2) + mbcnt64(E3);
          if (e0 && tp >= keep) s0 = false;  tp += e0 ? 1 : 0;
          if (e1 && tp >= keep) s1 = false;  tp += e1 ? 1 : 0;
          if (e2 && tp >= keep) s2 = false;  tp += e2 ? 1 : 0;
          if (e3 && tp >= keep) s3 = false;
          break;
        }
      }
      S0 = __ballot(s0); S1 = __ballot(s1); S2 = __ballot(s2); S3 = __ballot(s3);
    } else if (c < KK) {
      // add the (K-c) largest of the unselected rest; ties: add lowest d
      int need = KK - c;
      float m0 = s0 ? NINF : v0, m1 = s1 ? NINF : v1;
      float m2 = s2 ? NINF : v2, m3 = s3 ? NINF : v3;
      for (;;) {
        const float mm = wave_max_f32(fmaxf(fmaxf(m0, m1), fmaxf(m2, m3)));
        const bool e0 = (m0 == mm), e1 = (m1 == mm),
                   e2 = (m2 == mm), e3 = (m3 == mm);
        const unsigned long long E0 = __ballot(e0), E1 = __ballot(e1),
                                 E2 = __ballot(e2), E3 = __ballot(e3);
        const int cv = __popcll(E0) + __popcll(E1) + __popcll(E2) + __popcll(E3);
        if (cv <= need) {
          s0 |= e0; s1 |= e1; s2 |= e2; s3 |= e3;
          need -= cv;
          if (need == 0) break;
          m0 = e0 ? NINF : m0; m1 = e1 ? NINF : m1;
          m2 = e2 ? NINF : m2; m3 = e3 ? NINF : m3;
        } else {
          int tp = mbcnt64(E0) + mbcnt64(E1) + mbcnt64(E2) + mbcnt64(E3);
          if (e0 && tp < need) s0 = true;  tp += e0 ? 1 : 0;
          if (e1 && tp < need) s1 = true;  tp += e1 ? 1 : 0;
          if (e2 && tp < need) s2 = true;  tp += e2 ? 1 : 0;
          if (e3 && tp < need) s3 = true;
          break;
        }
      }
      S0 = __ballot(s0); S1 = __ballot(s1); S2 = __ballot(s2); S3 = __ballot(s3);
    }
    // c == KK: sel already exact, ballots already computed.

    // rank-by-index k = prefix count of selected below d (d = 4*lane + s)
    int kp = mbcnt64(S0) + mbcnt64(S1) + mbcnt64(S2) + mbcnt64(S3);
    const int b2 = 2 * lane;  // packed col: d=4l..4l+1 -> 2l, d=4l+2..3 -> 2l+1
    if (s0) atomicAdd(&cnt[kp * DH + b2],     1u);        kp += s0 ? 1 : 0;
    if (s1) atomicAdd(&cnt[kp * DH + b2],     0x10000u);  kp += s1 ? 1 : 0;
    if (s2) atomicAdd(&cnt[kp * DH + b2 + 1], 1u);        kp += s2 ? 1 : 0;
    if (s3) atomicAdd(&cnt[kp * DH + b2 + 1], 0x10000u);
  }

  __syncthreads();

  // sparse flush: count * (1/N) into zero-initialized out
  const float invn = 1.0f / (float)NN;
  float* ob = out + (size_t)b * KK * DD;
  for (int i = tid; i < LDSN; i += THREADS) {
    const unsigned cv = cnt[i];
    if (cv) {
      const int k   = i / DH;
      const int dd2 = i - k * DH;
      const unsigned lo = cv & 0xFFFFu, hi = cv >> 16;
      float* p = ob + k * DD + 2 * dd2;
      if (lo) atomicAdd(p,     (float)lo * invn);
      if (hi) atomicAdd(p + 1, (float)hi * invn);
    }
  }
}

extern "C" void kernel_launch(void* const* d_in, const int* in_sizes, int n_in,
                              void* d_out, int out_size, void* d_ws, size_t ws_size,
                              hipStream_t stream) {
  (void)in_sizes; (void)n_in; (void)ws_size;
  const float* x     = (const float*)d_in[0];
  const float* noise = (const float*)d_in[1];
  const float* sig   = (const float*)d_in[2];
  float* out = (float*)d_out;
  float* piv = (float*)d_ws;

  (void)hipMemsetAsync(d_out, 0, (size_t)out_size * sizeof(float), stream);
  pivot_kernel<<<dim3(BB), dim3(64), 0, stream>>>(x, piv);
  ptopk_kernel<<<dim3(BB * SPLIT), dim3(THREADS), 0, stream>>>(x, noise, sig, piv, out);
}

// Round 8
// 170.028 us; speedup vs baseline: 1.0148x; 1.0024x over previous
//
#include <hip/hip_runtime.h>

// PerturbedTopK: B=128, N=1000, D=196, K=48, sigma=0.05
//
// Per (b,n) row: exact top-K of x[b,:] + sigma*noise[b,n,:], tie-break lowest
// index first (jax.lax.top_k), then scatter 1/N at (b, rank_by_index, d).
//
// R8 = R7 resubmit (R7 never ran - GPU acquisition timeout).
// R7 vs R6 (flat ~58us across 3 algorithmically different rounds; VGPR_Count
// = 16 in ALL profiles -> diagnosis: launch_bounds with no min-waves arg let
// the compiler cap VGPRs at 16 -> heavy scratch spill in the row loop; spill
// round-trips are the invariant cost all previous edits failed to move):
//  - ONE change: __launch_bounds__(THREADS, 8) -> 8 waves/EU min -> 64-VGPR
//    budget; live state (~40 VGPRs) now fits, no spill. Algorithm identical
//    to R6 (DPP wave min/max, peel-to-selection, 256-thr blocks, SPLIT=16).

#define BB 128
#define NN 1000
#define DD 196
#define KK 48

constexpr int SPLIT   = 16;           // blocks per b (n-range split)
constexpr int THREADS = 256;          // 4 waves
constexpr int NWAVES  = THREADS / 64;
constexpr int DH      = DD / 2;       // 98 packed columns
constexpr int LDSN    = KK * DH;      // 4704 u32

__device__ __forceinline__ int mbcnt64(unsigned long long m) {
  return __builtin_amdgcn_mbcnt_hi((unsigned)(m >> 32),
         __builtin_amdgcn_mbcnt_lo((unsigned)m, 0));
}

// --- DPP wave reduction (VALU pipe; no LDS traffic) ---------------------
// ctrl: 0x110|k = row_shr:k, 0x142 = row_bcast15, 0x143 = row_bcast31.
// After the 6 steps lane 63 holds the full 64-lane reduction.
template <int CTRL>
__device__ __forceinline__ float dpp_min_step(float v) {
  int t = __builtin_amdgcn_update_dpp(__float_as_int(v), __float_as_int(v),
                                      CTRL, 0xF, 0xF, false);
  return fminf(v, __int_as_float(t));
}
template <int CTRL>
__device__ __forceinline__ float dpp_max_step(float v) {
  int t = __builtin_amdgcn_update_dpp(__float_as_int(v), __float_as_int(v),
                                      CTRL, 0xF, 0xF, false);
  return fmaxf(v, __int_as_float(t));
}

__device__ __forceinline__ float wave_min_f32(float m) {
  m = dpp_min_step<0x111>(m);  // row_shr:1
  m = dpp_min_step<0x112>(m);  // row_shr:2
  m = dpp_min_step<0x114>(m);  // row_shr:4
  m = dpp_min_step<0x118>(m);  // row_shr:8
  m = dpp_min_step<0x142>(m);  // row_bcast15
  m = dpp_min_step<0x143>(m);  // row_bcast31
  return __int_as_float(__builtin_amdgcn_readlane(__float_as_int(m), 63));
}
__device__ __forceinline__ float wave_max_f32(float m) {
  m = dpp_max_step<0x111>(m);
  m = dpp_max_step<0x112>(m);
  m = dpp_max_step<0x114>(m);
  m = dpp_max_step<0x118>(m);
  m = dpp_max_step<0x142>(m);
  m = dpp_max_step<0x143>(m);
  return __int_as_float(__builtin_amdgcn_readlane(__float_as_int(m), 63));
}

__device__ __forceinline__ unsigned key_of(float v) {
  unsigned u = __float_as_uint(v);
  return u ^ (0x80000000u | (unsigned)((int)u >> 31));
}

// piv[b] = exact 48th-largest VALUE of x[b] (as float); one wave per b.
__global__ __launch_bounds__(64, 4) void pivot_kernel(
    const float* __restrict__ x, float* __restrict__ piv) {
  const int b    = blockIdx.x;
  const int lane = threadIdx.x;
  const bool lv  = lane < 49;
  float4 xv = make_float4(0.f, 0.f, 0.f, 0.f);
  if (lv) xv = *reinterpret_cast<const float4*>(x + b * DD + 4 * lane);
  unsigned xk0 = lv ? key_of(xv.x) : 0u;
  unsigned xk1 = lv ? key_of(xv.y) : 0u;
  unsigned xk2 = lv ? key_of(xv.z) : 0u;
  unsigned xk3 = lv ? key_of(xv.w) : 0u;
  unsigned p = 0u;
  #pragma unroll
  for (int bit = 31; bit >= 0; --bit) {
    unsigned cand = p | (1u << bit);
    int c = __popcll(__ballot(xk0 >= cand)) + __popcll(__ballot(xk1 >= cand))
          + __popcll(__ballot(xk2 >= cand)) + __popcll(__ballot(xk3 >= cand));
    if (c >= KK) p = cand;
  }
  if (lane == 0) {
    unsigned u = (p & 0x80000000u) ? (p ^ 0x80000000u) : ~p;
    piv[b] = __uint_as_float(u);
  }
}

__global__ __launch_bounds__(THREADS, 8) void ptopk_kernel(
    const float* __restrict__ x, const float* __restrict__ noise,
    const float* __restrict__ sigp, const float* __restrict__ pivp,
    float* __restrict__ out) {
  __shared__ unsigned cnt[LDSN];
  const int tid   = threadIdx.x;
  const int b     = blockIdx.x / SPLIT;
  const int split = blockIdx.x % SPLIT;
  const int n0    = (split * NN) / SPLIT;        // 62/63-row ranges
  const int n1    = ((split + 1) * NN) / SPLIT;

  for (int i = tid; i < LDSN; i += THREADS) cnt[i] = 0u;
  __syncthreads();

  const float sigma = sigp[0];
  const float piv   = pivp[b];
  const int lane = tid & 63;
  const int wv   = tid >> 6;
  const bool lv  = lane < 49;  // 49 lanes * 4 floats = 196 = D
  const float PINF = __builtin_huge_valf();
  const float NINF = -__builtin_huge_valf();

  float4 xv = make_float4(0.f, 0.f, 0.f, 0.f);
  if (lv) xv = *reinterpret_cast<const float4*>(x + b * DD + 4 * lane);

  const float* nbase = noise + (size_t)b * NN * DD;

  // prefetched next-row noise
  float4 nv = make_float4(0.f, 0.f, 0.f, 0.f);
  if (lv && (n0 + wv) < n1)
    nv = *reinterpret_cast<const float4*>(nbase + (size_t)(n0 + wv) * DD + 4 * lane);

  for (int r = n0 + wv; r < n1; r += NWAVES) {
    const float4 cur = nv;
    if (lv && (r + NWAVES) < n1)
      nv = *reinterpret_cast<const float4*>(nbase + (size_t)(r + NWAVES) * DD + 4 * lane);

    // perturbed values; inactive lanes -> -inf (never selected)
    const float v0 = lv ? fmaf(sigma, cur.x, xv.x) : NINF;
    const float v1 = lv ? fmaf(sigma, cur.y, xv.y) : NINF;
    const float v2 = lv ? fmaf(sigma, cur.z, xv.z) : NINF;
    const float v3 = lv ? fmaf(sigma, cur.w, xv.w) : NINF;

    bool s0 = v0 > piv, s1 = v1 > piv, s2 = v2 > piv, s3 = v3 > piv;
    unsigned long long S0 = __ballot(s0), S1 = __ballot(s1),
                       S2 = __ballot(s2), S3 = __ballot(s3);
    const int c = __popcll(S0) + __popcll(S1) + __popcll(S2) + __popcll(S3);

    if (c > KK) {
      // remove the (c-K) smallest of the selected set; ties: drop highest d
      int need = c - KK;
      float m0 = s0 ? v0 : PINF, m1 = s1 ? v1 : PINF;
      float m2 = s2 ? v2 : PINF, m3 = s3 ? v3 : PINF;
      for (;;) {
        const float mm = wave_min_f32(fminf(fminf(m0, m1), fminf(m2, m3)));
        const bool e0 = (m0 == mm), e1 = (m1 == mm),
                   e2 = (m2 == mm), e3 = (m3 == mm);
        const unsigned long long E0 = __ballot(e0), E1 = __ballot(e1),
                                 E2 = __ballot(e2), E3 = __ballot(e3);
        const int cv = __popcll(E0) + __popcll(E1) + __popcll(E2) + __popcll(E3);
        if (cv <= need) {
          s0 &= !e0; s1 &= !e1; s2 &= !e2; s3 &= !e3;
          need -= cv;
          if (need == 0) break;
          m0 = e0 ? PINF : m0; m1 = e1 ? PINF : m1;
          m2 = e2 ? PINF : m2; m3 = e3 ? PINF : m3;
        } else {
          const int keep = cv - need;  // lowest-d `keep` ties stay selected
          int tp = mbcnt64(E0) + mbcnt64(E1) + mbcnt64(E2) + mbcnt64(E3);
          if (e0 && tp >= keep) s0 = false;  tp += e0 ? 1 : 0;
          if (e1 && tp >= keep) s1 = false;  tp += e1 ? 1 : 0;
          if (e2 && tp >= keep) s2 = false;  tp += e2 ? 1 : 0;
          if (e3 && tp >= keep) s3 = false;
          break;
        }
      }
      S0 = __ballot(s0); S1 = __ballot(s1); S2 = __ballot(s2); S3 = __ballot(s3);
    } else if (c < KK) {
      // add the (K-c) largest of the unselected rest; ties: add lowest d
      int need = KK - c;
      float m0 = s0 ? NINF : v0, m1 = s1 ? NINF : v1;
      float m2 = s2 ? NINF : v2, m3 = s3 ? NINF : v3;
      for (;;) {
        const float mm = wave_max_f32(fmaxf(fmaxf(m0, m1), fmaxf(m2, m3)));
        const bool e0 = (m0 == mm), e1 = (m1 == mm),
                   e2 = (m2 == mm), e3 = (m3 == mm);
        const unsigned long long E0 = __ballot(e0), E1 = __ballot(e1),
                                 E2 = __ballot(e2), E3 = __ballot(e3);
        const int cv = __popcll(E0) + __popcll(E1) + __popcll(E2) + __popcll(E3);
        if (cv <= need) {
          s0 |= e0; s1 |= e1; s2 |= e2; s3 |= e3;
          need -= cv;
          if (need == 0) break;
          m0 = e0 ? NINF : m0; m1 = e1 ? NINF : m1;
          m2 = e2 ? NINF : m2; m3 = e3 ? NINF : m3;
        } else {
          int tp = mbcnt64(E0) + mbcnt64(E1) + mbcnt64(E2) + mbcnt64(E3);
          if (e0 && tp < need) s0 = true;  tp += e0 ? 1 : 0;
          if (e1 && tp < need) s1 = true;  tp += e1 ? 1 : 0;
          if (e2 && tp < need) s2 = true;  tp += e2 ? 1 : 0;
          if (e3 && tp < need) s3 = true;
          break;
        }
      }
      S0 = __ballot(s0); S1 = __ballot(s1); S2 = __ballot(s2); S3 = __ballot(s3);
    }
    // c == KK: sel already exact, ballots already computed.

    // rank-by-index k = prefix count of selected below d (d = 4*lane + s)
    int kp = mbcnt64(S0) + mbcnt64(S1) + mbcnt64(S2) + mbcnt64(S3);
    const int b2 = 2 * lane;  // packed col: d=4l..4l+1 -> 2l, d=4l+2..3 -> 2l+1
    if (s0) atomicAdd(&cnt[kp * DH + b2],     1u);        kp += s0 ? 1 : 0;
    if (s1) atomicAdd(&cnt[kp * DH + b2],     0x10000u);  kp += s1 ? 1 : 0;
    if (s2) atomicAdd(&cnt[kp * DH + b2 + 1], 1u);        kp += s2 ? 1 : 0;
    if (s3) atomicAdd(&cnt[kp * DH + b2 + 1], 0x10000u);
  }

  __syncthreads();

  // sparse flush: count * (1/N) into zero-initialized out
  const float invn = 1.0f / (float)NN;
  float* ob = out + (size_t)b * KK * DD;
  for (int i = tid; i < LDSN; i += THREADS) {
    const unsigned cv = cnt[i];
    if (cv) {
      const int k   = i / DH;
      const int dd2 = i - k * DH;
      const unsigned lo = cv & 0xFFFFu, hi = cv >> 16;
      float* p = ob + k * DD + 2 * dd2;
      if (lo) atomicAdd(p,     (float)lo * invn);
      if (hi) atomicAdd(p + 1, (float)hi * invn);
    }
  }
}

extern "C" void kernel_launch(void* const* d_in, const int* in_sizes, int n_in,
                              void* d_out, int out_size, void* d_ws, size_t ws_size,
                              hipStream_t stream) {
  (void)in_sizes; (void)n_in; (void)ws_size;
  const float* x     = (const float*)d_in[0];
  const float* noise = (const float*)d_in[1];
  const float* sig   = (const float*)d_in[2];
  float* out = (float*)d_out;
  float* piv = (float*)d_ws;

  (void)hipMemsetAsync(d_out, 0, (size_t)out_size * sizeof(float), stream);
  pivot_kernel<<<dim3(BB), dim3(64), 0, stream>>>(x, piv);
  ptopk_kernel<<<dim3(BB * SPLIT), dim3(THREADS), 0, stream>>>(x, noise, sig, piv, out);
}